// Round 1
// baseline (450.363 us; speedup 1.0000x reference)
//
#include <hip/hip_runtime.h>
#include <stdint.h>

#define NTOK 8192   // B*T
#define D 1024
#define E 8
#define BM 128
#define BN 128
#define BK 32

typedef __attribute__((ext_vector_type(8))) short short8;
typedef __attribute__((ext_vector_type(4))) float f32x4;

// fp32 -> bf16 bits, round-to-nearest-even (inputs are finite gaussians; no NaN path)
__device__ __forceinline__ ushort f2bf(float f) {
  uint32_t x = __float_as_uint(f);
  x += 0x7FFFu + ((x >> 16) & 1u);
  return (ushort)(x >> 16);
}

__global__ __launch_bounds__(256) void convert_bf16_kernel(
    const float* __restrict__ src, ushort* __restrict__ dst, int n4) {
  int i = blockIdx.x * 256 + threadIdx.x;
  if (i >= n4) return;
  float4 v = ((const float4*)src)[i];
  ushort4 u;
  u.x = f2bf(v.x); u.y = f2bf(v.y); u.z = f2bf(v.z); u.w = f2bf(v.w);
  ((ushort4*)dst)[i] = u;
}

// One wave per token: fp32 gate logits, top-2, softmax, counting-sort into
// per-expert token lists.
__global__ __launch_bounds__(256) void gate_kernel(
    const float* __restrict__ x,     // input_feat [NTOK][D]
    const float* __restrict__ gW,    // [E][D]
    const float* __restrict__ gb,    // [E]
    int* __restrict__ cnt,           // [E]
    int* __restrict__ list,          // [E][NTOK]
    float* __restrict__ wlist)       // [E][NTOK]
{
  int wave = threadIdx.x >> 6;
  int lane = threadIdx.x & 63;
  int t = blockIdx.x * 4 + wave;

  const float4* xr = (const float4*)(x + (size_t)t * D) + lane * 4;
  float acc[E];
#pragma unroll
  for (int e = 0; e < E; ++e) acc[e] = 0.f;
#pragma unroll
  for (int q = 0; q < 4; ++q) {
    float4 xv = xr[q];
#pragma unroll
    for (int e = 0; e < E; ++e) {
      float4 wv = ((const float4*)(gW + e * D))[lane * 4 + q];
      acc[e] += xv.x * wv.x + xv.y * wv.y + xv.z * wv.z + xv.w * wv.w;
    }
  }
#pragma unroll
  for (int e = 0; e < E; ++e) {
    float v = acc[e];
#pragma unroll
    for (int off = 32; off > 0; off >>= 1) v += __shfl_xor(v, off, 64);
    acc[e] = v;
  }
  if (lane == 0) {
    float lg[E];
#pragma unroll
    for (int e = 0; e < E; ++e) lg[e] = acc[e] + gb[e];
    // top-2, first-index-wins on ties (matches jax.lax.top_k)
    int i0 = 0; float v0 = lg[0];
#pragma unroll
    for (int e = 1; e < E; ++e) { if (lg[e] > v0) { v0 = lg[e]; i0 = e; } }
    int i1 = -1; float v1 = -1e30f;
#pragma unroll
    for (int e = 0; e < E; ++e) { if (e != i0 && lg[e] > v1) { v1 = lg[e]; i1 = e; } }
    float e1 = __expf(v1 - v0);
    float inv = 1.f / (1.f + e1);
    float w0 = inv, w1 = e1 * inv;
    int s0 = atomicAdd(&cnt[i0], 1);
    list[i0 * NTOK + s0] = t; wlist[i0 * NTOK + s0] = w0;
    int s1 = atomicAdd(&cnt[i1], 1);
    list[i1 * NTOK + s1] = t; wlist[i1 * NTOK + s1] = w1;
  }
}

// Grouped GEMM: per expert e, C[m,n] = delta[tok_m,:] . W_e[n,:]  (B^T form),
// epilogue: out[tok_m, n] += weight_m * (C + bias_n)  via fp32 atomics.
__global__ __launch_bounds__(256) void moe_gemm_kernel(
    const float*  __restrict__ delta,  // [NTOK][D] fp32
    const ushort* __restrict__ Wb,     // [E][D][D] bf16 bits
    const float*  __restrict__ eb,     // expert_b [E][D]
    const int*    __restrict__ cnt,
    const int*    __restrict__ list,
    const float*  __restrict__ wlist,
    float*        __restrict__ out)    // [NTOK][D] fp32, pre-zeroed
{
  const int MT = NTOK / BM;   // 64
  const int NTI = D / BN;     // 8
  int bx = blockIdx.x;
  int e = bx / (MT * NTI);
  int rem = bx - e * (MT * NTI);
  int mt = rem / NTI;
  int nt = rem - mt * NTI;
  int M = cnt[e];
  int m0 = mt * BM;
  if (m0 >= M) return;
  int n0 = nt * BN;

  __shared__ ushort As[BM * BK];  // [m][k]
  __shared__ ushort Bs[BN * BK];  // [n][k]

  int tid = threadIdx.x;
  int wave = tid >> 6;
  int lane = tid & 63;
  int wm = wave >> 1;
  int wn = wave & 1;
  const int c = lane & 15;
  const int q = lane >> 4;

  // A staging: thread covers rows (arow + 32p), cols [acol, acol+4)
  int arow = tid >> 3;            // 0..31
  int acol = (tid & 7) << 2;      // 0,4,...,28
  const int* listE = list + e * NTOK;
  const float* aptr[4];
#pragma unroll
  for (int p = 0; p < 4; ++p) {
    int r = m0 + arow + 32 * p;
    int tok = listE[r < M ? r : m0];   // clamp padded rows to a valid token
    aptr[p] = delta + (size_t)tok * D + acol;
  }

  // B staging via global_load_lds (16B/lane, wave-uniform LDS base + lane*16)
  const ushort* WbE = Wb + ((size_t)e << 20);
  const ushort* bptr[2];
  ushort* blds[2];
#pragma unroll
  for (int sub = 0; sub < 2; ++sub) {
    int row = wave * 32 + sub * 16 + (lane >> 2);
    bptr[sub] = WbE + (size_t)(n0 + row) * D + ((lane & 3) << 3);
    blds[sub] = &Bs[(wave * 32 + sub * 16) * BK];
  }

  f32x4 acc[4][4];
#pragma unroll
  for (int i = 0; i < 4; ++i)
#pragma unroll
    for (int j = 0; j < 4; ++j)
      acc[i][j] = (f32x4){0.f, 0.f, 0.f, 0.f};

  for (int k0 = 0; k0 < D; k0 += BK) {
#pragma unroll
    for (int sub = 0; sub < 2; ++sub) {
      __builtin_amdgcn_global_load_lds(
          (const __attribute__((address_space(1))) void*)(bptr[sub] + k0),
          (__attribute__((address_space(3))) void*)blds[sub], 16, 0, 0);
    }
#pragma unroll
    for (int p = 0; p < 4; ++p) {
      float4 v = *(const float4*)(aptr[p] + k0);
      ushort4 u;
      u.x = f2bf(v.x); u.y = f2bf(v.y); u.z = f2bf(v.z); u.w = f2bf(v.w);
      *(ushort4*)&As[(arow + 32 * p) * BK + acol] = u;
    }
    __syncthreads();

    short8 a[4], b[4];
#pragma unroll
    for (int i = 0; i < 4; ++i) {
      a[i] = *(const short8*)&As[(wm * 64 + i * 16 + c) * BK + q * 8];
      b[i] = *(const short8*)&Bs[(wn * 64 + i * 16 + c) * BK + q * 8];
    }
#pragma unroll
    for (int i = 0; i < 4; ++i)
#pragma unroll
      for (int j = 0; j < 4; ++j)
        acc[i][j] = __builtin_amdgcn_mfma_f32_16x16x32_bf16(a[i], b[j], acc[i][j], 0, 0, 0);
    __syncthreads();
  }

  // Epilogue: C/D layout col=lane&15, row=(lane>>4)*4+reg
  float bias[4];
#pragma unroll
  for (int j = 0; j < 4; ++j)
    bias[j] = eb[e * D + n0 + wn * 64 + j * 16 + c];
  const float* wlE = wlist + e * NTOK;
#pragma unroll
  for (int i = 0; i < 4; ++i) {
#pragma unroll
    for (int r = 0; r < 4; ++r) {
      int m = m0 + wm * 64 + i * 16 + q * 4 + r;
      if (m < M) {
        int tok = listE[m];
        float w = wlE[m];
        float* orow = out + (size_t)tok * D + n0 + wn * 64 + c;
#pragma unroll
        for (int j = 0; j < 4; ++j)
          atomicAdd(&orow[j * 16], (acc[i][j][r] + bias[j]) * w);
      }
    }
  }
}

extern "C" void kernel_launch(void* const* d_in, const int* in_sizes, int n_in,
                              void* d_out, int out_size, void* d_ws, size_t ws_size,
                              hipStream_t stream) {
  const float* input_feat = (const float*)d_in[0];
  const float* delta      = (const float*)d_in[1];
  const float* gate_W     = (const float*)d_in[2];
  const float* gate_b     = (const float*)d_in[3];
  const float* expert_W   = (const float*)d_in[4];
  const float* expert_b   = (const float*)d_in[5];
  float* out = (float*)d_out;

  // workspace layout: Wb (16 MiB) | cnt (256 B) | list (1 MiB/4) | wlist
  char* ws = (char*)d_ws;
  ushort* Wb   = (ushort*)ws;
  int*    cnt  = (int*)(ws + 16777216);
  int*    list = (int*)(ws + 16777216 + 256);
  float* wlist = (float*)(ws + 16777216 + 256 + NTOK * E * 4);

  hipMemsetAsync(d_out, 0, (size_t)NTOK * D * sizeof(float), stream);
  hipMemsetAsync(cnt, 0, E * sizeof(int), stream);

  int n4 = E * D * D / 4;
  convert_bf16_kernel<<<(n4 + 255) / 256, 256, 0, stream>>>(expert_W, Wb, n4);
  gate_kernel<<<NTOK / 4, 256, 0, stream>>>(input_feat, gate_W, gate_b, cnt, list, wlist);
  moe_gemm_kernel<<<E * (NTOK / BM) * (D / BN), 256, 0, stream>>>(
      delta, Wb, expert_b, cnt, list, wlist, out);
}

// Round 4
// 264.887 us; speedup vs baseline: 1.7002x; 1.7002x over previous
//
#include <hip/hip_runtime.h>
#include <stdint.h>

#define NTOK 8192   // B*T
#define D 1024
#define E 8
#define BM 128
#define BN 128
#define BK 32

typedef __attribute__((ext_vector_type(8))) short short8;
typedef __attribute__((ext_vector_type(4))) float f32x4;

// fp32 -> bf16 bits, round-to-nearest-even
__device__ __forceinline__ ushort f2bf(float f) {
  uint32_t x = __float_as_uint(f);
  x += 0x7FFFu + ((x >> 16) & 1u);
  return (ushort)(x >> 16);
}

__global__ __launch_bounds__(256) void convert_bf16_kernel(
    const float* __restrict__ src, ushort* __restrict__ dst, int n4) {
  int i = blockIdx.x * 256 + threadIdx.x;
  if (i >= n4) return;
  float4 v = ((const float4*)src)[i];
  ushort4 u;
  u.x = f2bf(v.x); u.y = f2bf(v.y); u.z = f2bf(v.z); u.w = f2bf(v.w);
  ((ushort4*)dst)[i] = u;
}

// Phase 1: wave per token — fp32 logits, top-2, softmax. NO global atomics.
__global__ __launch_bounds__(256) void gate_topk_kernel(
    const float* __restrict__ x,     // input_feat [NTOK][D]
    const float* __restrict__ gW,    // [E][D]
    const float* __restrict__ gb,    // [E]
    int*   __restrict__ idx01,       // [NTOK]  (i0 | i1<<16)
    float2* __restrict__ w01)        // [NTOK]  (w0, w1)
{
  int wave = threadIdx.x >> 6;
  int lane = threadIdx.x & 63;
  int t = blockIdx.x * 4 + wave;

  const float4* xr = (const float4*)(x + (size_t)t * D) + lane * 4;
  float acc[E];
#pragma unroll
  for (int e = 0; e < E; ++e) acc[e] = 0.f;
#pragma unroll
  for (int q = 0; q < 4; ++q) {
    float4 xv = xr[q];
#pragma unroll
    for (int e = 0; e < E; ++e) {
      float4 wv = ((const float4*)(gW + e * D))[lane * 4 + q];
      acc[e] += xv.x * wv.x + xv.y * wv.y + xv.z * wv.z + xv.w * wv.w;
    }
  }
#pragma unroll
  for (int e = 0; e < E; ++e) {
    float v = acc[e];
#pragma unroll
    for (int off = 32; off > 0; off >>= 1) v += __shfl_xor(v, off, 64);
    acc[e] = v;
  }
  if (lane == 0) {
    float lg[E];
#pragma unroll
    for (int e = 0; e < E; ++e) lg[e] = acc[e] + gb[e];
    int i0 = 0; float v0 = lg[0];
#pragma unroll
    for (int e = 1; e < E; ++e) { if (lg[e] > v0) { v0 = lg[e]; i0 = e; } }
    int i1 = -1; float v1 = -1e30f;
#pragma unroll
    for (int e = 0; e < E; ++e) { if (e != i0 && lg[e] > v1) { v1 = lg[e]; i1 = e; } }
    float e1 = __expf(v1 - v0);
    float inv = 1.f / (1.f + e1);
    idx01[t] = i0 | (i1 << 16);
    w01[t] = make_float2(inv, e1 * inv);
  }
}

// Phase 2: counting-sort into per-expert lists. LDS histogram per block,
// 8 global atomics per block (32 blocks -> 256 total, no long chains).
// Final out = w0*y0 + w1*y1 via two atomicAdds onto 0 — fp add is
// commutative, so nondeterministic list order does not change the result.
__global__ __launch_bounds__(256) void bin_kernel(
    const int*    __restrict__ idx01,
    const float2* __restrict__ w01,
    int*   __restrict__ cnt,     // [E], zeroed
    int*   __restrict__ list,    // [E][NTOK]
    float* __restrict__ wlist)   // [E][NTOK]
{
  __shared__ int hist[E];
  __shared__ int base[E];
  int tid = threadIdx.x;
  int t = blockIdx.x * 256 + tid;
  if (tid < E) hist[tid] = 0;
  __syncthreads();

  int packed = idx01[t];
  float2 w = w01[t];
  int i0 = packed & 0xFFFF, i1 = packed >> 16;
  int r0 = atomicAdd(&hist[i0], 1);
  int r1 = atomicAdd(&hist[i1], 1);
  __syncthreads();
  if (tid < E) base[tid] = atomicAdd(&cnt[tid], hist[tid]);
  __syncthreads();

  int s0 = base[i0] + r0;
  list[i0 * NTOK + s0] = t; wlist[i0 * NTOK + s0] = w.x;
  int s1 = base[i1] + r1;
  list[i1 * NTOK + s1] = t; wlist[i1 * NTOK + s1] = w.y;
}

// Grouped GEMM: per expert e, C[m,n] = delta_bf16[tok_m,:] . W_e[n,:] (B^T),
// epilogue: out[tok_m, n] += weight_m * (C + bias_n)  via fp32 atomics.
// Both A and B tiles staged via global_load_lds width=16 (m97 structure).
__global__ __launch_bounds__(256) void moe_gemm_kernel(
    const ushort* __restrict__ Db,     // delta bf16 [NTOK][D]
    const ushort* __restrict__ Wb,     // [E][D][D] bf16 bits
    const float*  __restrict__ eb,     // expert_b [E][D]
    const int*    __restrict__ cnt,
    const int*    __restrict__ list,
    const float*  __restrict__ wlist,
    float*        __restrict__ out)    // [NTOK][D] fp32, pre-zeroed
{
  const int MT = NTOK / BM;   // 64
  const int NTI = D / BN;     // 8
  int bx = blockIdx.x;
  int e = bx / (MT * NTI);
  int rem = bx - e * (MT * NTI);
  int mt = rem / NTI;
  int nt = rem - mt * NTI;
  int M = cnt[e];
  int m0 = mt * BM;
  if (m0 >= M) return;
  int n0 = nt * BN;

  __shared__ ushort As[BM * BK];  // [m][k], 64 B rows
  __shared__ ushort Bs[BN * BK];  // [n][k]

  int tid = threadIdx.x;
  int wave = tid >> 6;
  int lane = tid & 63;
  int wm = wave >> 1;
  int wn = wave & 1;
  const int c = lane & 15;
  const int q = lane >> 4;

  const int* listE = list + e * NTOK;

  // A staging via global_load_lds: per-lane global gather, wave-uniform LDS
  // base + lane*16. Lane l covers row (p*64 + wave*16 + (l>>2)), cols (l&3)*8.
  const ushort* aptr[2];
  ushort* alds[2];
#pragma unroll
  for (int p = 0; p < 2; ++p) {
    int r = m0 + p * 64 + wave * 16 + (lane >> 2);
    int tok = listE[r < M ? r : m0];   // clamp padded rows to a valid token
    aptr[p] = Db + (size_t)tok * D + ((lane & 3) << 3);
    alds[p] = &As[(p * 64 + wave * 16) * BK];
  }

  // B staging: lane l covers row (wave*32 + sub*16 + (l>>2)), cols (l&3)*8.
  const ushort* WbE = Wb + ((size_t)e << 20);
  const ushort* bptr[2];
  ushort* blds[2];
#pragma unroll
  for (int sub = 0; sub < 2; ++sub) {
    int row = wave * 32 + sub * 16 + (lane >> 2);
    bptr[sub] = WbE + (size_t)(n0 + row) * D + ((lane & 3) << 3);
    blds[sub] = &Bs[(wave * 32 + sub * 16) * BK];
  }

  f32x4 acc[4][4];
#pragma unroll
  for (int i = 0; i < 4; ++i)
#pragma unroll
    for (int j = 0; j < 4; ++j)
      acc[i][j] = (f32x4){0.f, 0.f, 0.f, 0.f};

  for (int k0 = 0; k0 < D; k0 += BK) {
#pragma unroll
    for (int p = 0; p < 2; ++p) {
      __builtin_amdgcn_global_load_lds(
          (const __attribute__((address_space(1))) void*)(aptr[p] + k0),
          (__attribute__((address_space(3))) void*)alds[p], 16, 0, 0);
    }
#pragma unroll
    for (int sub = 0; sub < 2; ++sub) {
      __builtin_amdgcn_global_load_lds(
          (const __attribute__((address_space(1))) void*)(bptr[sub] + k0),
          (__attribute__((address_space(3))) void*)blds[sub], 16, 0, 0);
    }
    __syncthreads();

    short8 a[4], b[4];
#pragma unroll
    for (int i = 0; i < 4; ++i) {
      a[i] = *(const short8*)&As[(wm * 64 + i * 16 + c) * BK + q * 8];
      b[i] = *(const short8*)&Bs[(wn * 64 + i * 16 + c) * BK + q * 8];
    }
#pragma unroll
    for (int i = 0; i < 4; ++i)
#pragma unroll
      for (int j = 0; j < 4; ++j)
        acc[i][j] = __builtin_amdgcn_mfma_f32_16x16x32_bf16(a[i], b[j], acc[i][j], 0, 0, 0);
    __syncthreads();
  }

  // Epilogue: C/D layout col=lane&15, row=(lane>>4)*4+reg
  float bias[4];
#pragma unroll
  for (int j = 0; j < 4; ++j)
    bias[j] = eb[e * D + n0 + wn * 64 + j * 16 + c];
  const float* wlE = wlist + e * NTOK;
#pragma unroll
  for (int i = 0; i < 4; ++i) {
#pragma unroll
    for (int r = 0; r < 4; ++r) {
      int m = m0 + wm * 64 + i * 16 + q * 4 + r;
      if (m < M) {
        int tok = listE[m];
        float w = wlE[m];
        float* orow = out + (size_t)tok * D + n0 + wn * 64 + c;
#pragma unroll
        for (int j = 0; j < 4; ++j)
          atomicAdd(&orow[j * 16], (acc[i][j][r] + bias[j]) * w);
      }
    }
  }
}

extern "C" void kernel_launch(void* const* d_in, const int* in_sizes, int n_in,
                              void* d_out, int out_size, void* d_ws, size_t ws_size,
                              hipStream_t stream) {
  const float* input_feat = (const float*)d_in[0];
  const float* delta      = (const float*)d_in[1];
  const float* gate_W     = (const float*)d_in[2];
  const float* gate_b     = (const float*)d_in[3];
  const float* expert_W   = (const float*)d_in[4];
  const float* expert_b   = (const float*)d_in[5];
  float* out = (float*)d_out;

  // workspace layout: Wb (16 MiB) | Db (16 MiB) | cnt | list | wlist | idx01 | w01
  char* ws = (char*)d_ws;
  ushort* Wb    = (ushort*)ws;                         // E*D*D bf16 = 16 MiB
  ushort* Db    = (ushort*)(ws + 16777216);            // NTOK*D bf16 = 16 MiB
  char*   meta  = ws + 2 * 16777216;
  int*    cnt   = (int*)meta;
  int*    list  = (int*)(meta + 256);
  float*  wlist = (float*)(meta + 256 + NTOK * E * 4);
  int*    idx01 = (int*)(meta + 256 + 2 * NTOK * E * 4);
  float2* w01   = (float2*)(meta + 256 + 2 * NTOK * E * 4 + NTOK * 4);

  hipMemsetAsync(d_out, 0, (size_t)NTOK * D * sizeof(float), stream);
  hipMemsetAsync(cnt, 0, E * sizeof(int), stream);

  int nW4 = E * D * D / 4;
  int nD4 = NTOK * D / 4;
  convert_bf16_kernel<<<(nW4 + 255) / 256, 256, 0, stream>>>(expert_W, Wb, nW4);
  convert_bf16_kernel<<<(nD4 + 255) / 256, 256, 0, stream>>>(delta, Db, nD4);
  gate_topk_kernel<<<NTOK / 4, 256, 0, stream>>>(input_feat, gate_W, gate_b, idx01, w01);
  bin_kernel<<<NTOK / 256, 256, 0, stream>>>(idx01, w01, cnt, list, wlist);
  moe_gemm_kernel<<<E * (NTOK / BM) * (D / BN), 256, 0, stream>>>(
      Db, Wb, expert_b, cnt, list, wlist, out);
}

// Round 5
// 236.817 us; speedup vs baseline: 1.9017x; 1.1185x over previous
//
#include <hip/hip_runtime.h>
#include <stdint.h>

#define NTOK 8192   // B*T
#define D 1024
#define E 8
#define BM 128
#define BN 64
#define BK 64

typedef __attribute__((ext_vector_type(8))) short short8;
typedef __attribute__((ext_vector_type(4))) float f32x4;

// fp32 -> bf16 bits, round-to-nearest-even
__device__ __forceinline__ ushort f2bf(float f) {
  uint32_t x = __float_as_uint(f);
  x += 0x7FFFu + ((x >> 16) & 1u);
  return (ushort)(x >> 16);
}

// One fused dispatch: convert expert_W -> bf16, convert delta -> bf16,
// zero out (32 MB), zero cnt. Removes 3 extra dispatches (~15 us each of
// graph-replay overhead) vs separate kernels + memsets.
#define NW4 2097152   // E*D*D/4
#define ND4 2097152   // NTOK*D/4
#define NO4 2097152   // NTOK*D/4 (out, float4)
__global__ __launch_bounds__(256) void convert_zero_kernel(
    const float* __restrict__ expert_W, const float* __restrict__ delta,
    ushort* __restrict__ Wb, ushort* __restrict__ Db,
    float* __restrict__ out, int* __restrict__ cnt) {
  int i = blockIdx.x * 256 + threadIdx.x;
  if (i < E) cnt[i] = 0;
  if (i < NW4) {
    float4 v = ((const float4*)expert_W)[i];
    ushort4 u; u.x = f2bf(v.x); u.y = f2bf(v.y); u.z = f2bf(v.z); u.w = f2bf(v.w);
    ((ushort4*)Wb)[i] = u;
  } else if (i < NW4 + ND4) {
    int j = i - NW4;
    float4 v = ((const float4*)delta)[j];
    ushort4 u; u.x = f2bf(v.x); u.y = f2bf(v.y); u.z = f2bf(v.z); u.w = f2bf(v.w);
    ((ushort4*)Db)[j] = u;
  } else {
    int j = i - NW4 - ND4;
    ((float4*)out)[j] = (float4){0.f, 0.f, 0.f, 0.f};
  }
}

// Wave per token: fp32 logits, top-2, softmax. No global atomics.
__global__ __launch_bounds__(256) void gate_topk_kernel(
    const float* __restrict__ x, const float* __restrict__ gW,
    const float* __restrict__ gb,
    int* __restrict__ idx01, float2* __restrict__ w01) {
  int wave = threadIdx.x >> 6;
  int lane = threadIdx.x & 63;
  int t = blockIdx.x * 4 + wave;

  const float4* xr = (const float4*)(x + (size_t)t * D) + lane * 4;
  float acc[E];
#pragma unroll
  for (int e = 0; e < E; ++e) acc[e] = 0.f;
#pragma unroll
  for (int q = 0; q < 4; ++q) {
    float4 xv = xr[q];
#pragma unroll
    for (int e = 0; e < E; ++e) {
      float4 wv = ((const float4*)(gW + e * D))[lane * 4 + q];
      acc[e] += xv.x * wv.x + xv.y * wv.y + xv.z * wv.z + xv.w * wv.w;
    }
  }
#pragma unroll
  for (int e = 0; e < E; ++e) {
    float v = acc[e];
#pragma unroll
    for (int off = 32; off > 0; off >>= 1) v += __shfl_xor(v, off, 64);
    acc[e] = v;
  }
  if (lane == 0) {
    float lg[E];
#pragma unroll
    for (int e = 0; e < E; ++e) lg[e] = acc[e] + gb[e];
    int i0 = 0; float v0 = lg[0];
#pragma unroll
    for (int e = 1; e < E; ++e) { if (lg[e] > v0) { v0 = lg[e]; i0 = e; } }
    int i1 = -1; float v1 = -1e30f;
#pragma unroll
    for (int e = 0; e < E; ++e) { if (e != i0 && lg[e] > v1) { v1 = lg[e]; i1 = e; } }
    float e1 = __expf(v1 - v0);
    float inv = 1.f / (1.f + e1);
    idx01[t] = i0 | (i1 << 16);
    w01[t] = make_float2(inv, e1 * inv);
  }
}

// Counting-sort into per-expert lists. LDS histogram, 8 global atomics/block.
__global__ __launch_bounds__(256) void bin_kernel(
    const int* __restrict__ idx01, const float2* __restrict__ w01,
    int* __restrict__ cnt, int* __restrict__ list, float* __restrict__ wlist) {
  __shared__ int hist[E];
  __shared__ int base[E];
  int tid = threadIdx.x;
  int t = blockIdx.x * 256 + tid;
  if (tid < E) hist[tid] = 0;
  __syncthreads();

  int packed = idx01[t];
  float2 w = w01[t];
  int i0 = packed & 0xFFFF, i1 = packed >> 16;
  int r0 = atomicAdd(&hist[i0], 1);
  int r1 = atomicAdd(&hist[i1], 1);
  __syncthreads();
  if (tid < E) base[tid] = atomicAdd(&cnt[tid], hist[tid]);
  __syncthreads();

  int s0 = base[i0] + r0;
  list[i0 * NTOK + s0] = t; wlist[i0 * NTOK + s0] = w.x;
  int s1 = base[i1] + r1;
  list[i1 * NTOK + s1] = t; wlist[i1 * NTOK + s1] = w.y;
}

// Grouped GEMM v2: BM=128,BN=64,BK=64. 16 K-iters (half the barrier drains),
// 2048 working blocks (8/CU), XOR-swizzled LDS (conflict-free ds_read_b128),
// XCD-affine mapping (bx%8 == nt%8 -> B-tile stays hot in one XCD's L2).
// LDS layout: slot (row, s) holds global granule s ^ (row&7)  (granule=16B).
__global__ __launch_bounds__(256) void moe_gemm_kernel(
    const ushort* __restrict__ Db, const ushort* __restrict__ Wb,
    const float* __restrict__ eb, const int* __restrict__ cnt,
    const int* __restrict__ list, const float* __restrict__ wlist,
    float* __restrict__ out) {
  // bx = mt*128 + e*16 + nt  (mt slow: first 2048 blocks all alive)
  int bx = blockIdx.x;
  int mt = bx >> 7;
  int rem = bx & 127;
  int e = rem >> 4;
  int nt = rem & 15;
  int M = cnt[e];
  int m0 = mt * BM;
  if (m0 >= M) return;
  int n0 = nt * BN;

  __shared__ ushort As[BM * BK];  // 16 KB, row stride 64 elem (128 B)
  __shared__ ushort Bs[BN * BK];  // 8 KB

  int tid = threadIdx.x;
  int wave = tid >> 6;
  int lane = tid & 63;
  int wm = wave >> 1;   // 0..1 : 64 rows
  int wn = wave & 1;    // 0..1 : 32 cols
  const int c = lane & 15;
  const int q = lane >> 4;

  const int* listE = list + e * NTOK;

  // Staging: inst covers 8 rows x 8 granules; lane l -> row +(l>>3), slot l&7,
  // fetches global granule (l&7)^(l>>3)  (row&7 == l>>3 since bases are %8==0).
  int rloc = lane >> 3;                 // 0..7
  int gglob = (lane & 7) ^ rloc;        // swizzled source granule
  const ushort* aptr[4];
  ushort* alds[4];
#pragma unroll
  for (int p = 0; p < 4; ++p) {
    int r = m0 + wave * 32 + p * 8 + rloc;
    int tok = listE[r < M ? r : m0];    // clamp padded rows
    aptr[p] = Db + (size_t)tok * D + gglob * 8;
    alds[p] = &As[(wave * 32 + p * 8) * BK];
  }
  const ushort* WbE = Wb + ((size_t)e << 20);
  const ushort* bptr[2];
  ushort* blds[2];
#pragma unroll
  for (int sub = 0; sub < 2; ++sub) {
    int row = n0 + wave * 16 + sub * 8 + rloc;
    bptr[sub] = WbE + (size_t)row * D + gglob * 8;
    blds[sub] = &Bs[(wave * 16 + sub * 8) * BK];
  }

  f32x4 acc[4][2];
#pragma unroll
  for (int i = 0; i < 4; ++i)
#pragma unroll
    for (int j = 0; j < 2; ++j)
      acc[i][j] = (f32x4){0.f, 0.f, 0.f, 0.f};

  for (int k0 = 0; k0 < D; k0 += BK) {
#pragma unroll
    for (int p = 0; p < 4; ++p)
      __builtin_amdgcn_global_load_lds(
          (const __attribute__((address_space(1))) void*)(aptr[p] + k0),
          (__attribute__((address_space(3))) void*)alds[p], 16, 0, 0);
#pragma unroll
    for (int sub = 0; sub < 2; ++sub)
      __builtin_amdgcn_global_load_lds(
          (const __attribute__((address_space(1))) void*)(bptr[sub] + k0),
          (__attribute__((address_space(3))) void*)blds[sub], 16, 0, 0);
    __syncthreads();

#pragma unroll
    for (int s = 0; s < 2; ++s) {
      // granule index g = s*4+q; swizzled LDS slot = g ^ (row&7), row&7 = c&7
      int sw = (((s * 4 + q) ^ (c & 7)) * 8);
      short8 a[4], b[2];
#pragma unroll
      for (int i = 0; i < 4; ++i)
        a[i] = *(const short8*)&As[(wm * 64 + i * 16 + c) * BK + sw];
#pragma unroll
      for (int j = 0; j < 2; ++j)
        b[j] = *(const short8*)&Bs[(wn * 32 + j * 16 + c) * BK + sw];
#pragma unroll
      for (int i = 0; i < 4; ++i)
#pragma unroll
        for (int j = 0; j < 2; ++j)
          acc[i][j] = __builtin_amdgcn_mfma_f32_16x16x32_bf16(a[i], b[j], acc[i][j], 0, 0, 0);
    }
    __syncthreads();
  }

  // Epilogue: C/D layout col=lane&15, row=(lane>>4)*4+reg
  float bias[2];
#pragma unroll
  for (int j = 0; j < 2; ++j)
    bias[j] = eb[e * D + n0 + wn * 32 + j * 16 + c];
  const float* wlE = wlist + e * NTOK;
#pragma unroll
  for (int i = 0; i < 4; ++i) {
#pragma unroll
    for (int r = 0; r < 4; ++r) {
      int m = m0 + wm * 64 + i * 16 + q * 4 + r;
      if (m < M) {
        int tok = listE[m];
        float w = wlE[m];
        float* orow = out + (size_t)tok * D + n0 + wn * 32 + c;
#pragma unroll
        for (int j = 0; j < 2; ++j)
          atomicAdd(&orow[j * 16], (acc[i][j][r] + bias[j]) * w);
      }
    }
  }
}

extern "C" void kernel_launch(void* const* d_in, const int* in_sizes, int n_in,
                              void* d_out, int out_size, void* d_ws, size_t ws_size,
                              hipStream_t stream) {
  const float* input_feat = (const float*)d_in[0];
  const float* delta      = (const float*)d_in[1];
  const float* gate_W     = (const float*)d_in[2];
  const float* gate_b     = (const float*)d_in[3];
  const float* expert_W   = (const float*)d_in[4];
  const float* expert_b   = (const float*)d_in[5];
  float* out = (float*)d_out;

  // ws: Wb 16MiB | Db 16MiB | cnt | list | wlist | idx01 | w01
  char* ws = (char*)d_ws;
  ushort* Wb    = (ushort*)ws;
  ushort* Db    = (ushort*)(ws + 16777216);
  char*   meta  = ws + 2 * 16777216;
  int*    cnt   = (int*)meta;
  int*    list  = (int*)(meta + 256);
  float*  wlist = (float*)(meta + 256 + NTOK * E * 4);
  int*    idx01 = (int*)(meta + 256 + 2 * NTOK * E * 4);
  float2* w01   = (float2*)(meta + 256 + 2 * NTOK * E * 4 + NTOK * 4);

  int total4 = NW4 + ND4 + NO4;
  convert_zero_kernel<<<total4 / 256, 256, 0, stream>>>(expert_W, delta, Wb, Db, out, cnt);
  gate_topk_kernel<<<NTOK / 4, 256, 0, stream>>>(input_feat, gate_W, gate_b, idx01, w01);
  bin_kernel<<<NTOK / 256, 256, 0, stream>>>(idx01, w01, cnt, list, wlist);
  moe_gemm_kernel<<<(NTOK / BM) * 128, 256, 0, stream>>>(
      Db, Wb, expert_b, cnt, list, wlist, out);
}